// Round 15
// baseline (387.370 us; speedup 1.0000x reference)
//
#include <hip/hip_runtime.h>

typedef __attribute__((ext_vector_type(8))) short short8;
typedef __attribute__((ext_vector_type(4))) float f32x4;

static __device__ __forceinline__ unsigned short f2bf(float f) {
    union { float f; unsigned int u; } v; v.f = f;
    unsigned int r = v.u + 0x7fffu + ((v.u >> 16) & 1u);  // RNE
    return (unsigned short)(r >> 16);
}

static __device__ __forceinline__ float bf2f(unsigned short b) {
    union { unsigned int u; float f; } v; v.u = (unsigned int)b << 16; return v.f;
}

// HW packed f32->bf16 (RNE): one instruction per 2 elements.
static __device__ __forceinline__ short8 pack8(float4 a, float4 b) {
    union { unsigned int u[4]; short8 s; } r;
    asm("v_cvt_pk_bf16_f32 %0, %1, %2" : "=v"(r.u[0]) : "v"(a.x), "v"(a.y));
    asm("v_cvt_pk_bf16_f32 %0, %1, %2" : "=v"(r.u[1]) : "v"(a.z), "v"(a.w));
    asm("v_cvt_pk_bf16_f32 %0, %1, %2" : "=v"(r.u[2]) : "v"(b.x), "v"(b.y));
    asm("v_cvt_pk_bf16_f32 %0, %1, %2" : "=v"(r.u[3]) : "v"(b.z), "v"(b.w));
    return r.s;
}

static __device__ __forceinline__ void dma16(const void* g, void* l) {
    __builtin_amdgcn_global_load_lds(
        (const __attribute__((address_space(1))) unsigned int*)g,
        (__attribute__((address_space(3))) unsigned int*)l, 16, 0, 0);
}

static __device__ __forceinline__ float4 lds_rd16(const float* buf, int boff, int sw) {
    return *(const float4*)((const char*)buf + (boff ^ sw));
}

__global__ void k_zero(uint4* p, int n16) {
    int i = blockIdx.x * blockDim.x + threadIdx.x;
    if (i < n16) p[i] = uint4{0u, 0u, 0u, 0u};
}

// Pack W1,W2 (f32 [128][256]) into 4 fragment-ordered bf16 arrays.
__global__ void k_convw(const float* __restrict__ W1, const float* __restrict__ W2,
                        unsigned short* W1af, unsigned short* W1bf,
                        unsigned short* W2af, unsigned short* W2bf) {
    int T = blockIdx.x * 256 + threadIdx.x;   // 8192 total
    int mat = T >> 11;
    int rem = T & 2047;
    int f = rem >> 6, lane = rem & 63;
    int wc = f >> 4, t = (f >> 2) & 3, kk = f & 3;
    int p = lane & 15, q = lane >> 4;
    int row = wc * 64 + t * 16 + p;
    int col = (mat & 1) * 128 + kk * 32 + q * 8;
    const float* src = (mat < 2 ? W1 : W2) + row * 256 + col;
    unsigned short* dst = (mat == 0 ? W1af : mat == 1 ? W1bf : mat == 2 ? W2af : W2bf);
    short8 v;
#pragma unroll
    for (int j = 0; j < 8; ++j) v[j] = (short)f2bf(src[j]);
    *(short8*)&dst[(size_t)f * 512 + lane * 8] = v;
}

__global__ void k_mark(const int* __restrict__ ids, int* __restrict__ cum, int n) {
    int i = blockIdx.x * blockDim.x + threadIdx.x;
    if (i < n) cum[ids[i]] = 1;
}

// 2-level scan: per-block inclusive scan of 1024 ints + block sums
__global__ __launch_bounds__(256) void k_scan1(int* __restrict__ cum, int* __restrict__ bsum, int G) {
    __shared__ int ws[4];
    int tid = threadIdx.x;
    int base = blockIdx.x * 1024 + tid * 4;
    int a0 = 0, a1 = 0, a2 = 0, a3 = 0;
    if (base + 0 < G) a0 = cum[base + 0];
    if (base + 1 < G) a1 = cum[base + 1];
    if (base + 2 < G) a2 = cum[base + 2];
    if (base + 3 < G) a3 = cum[base + 3];
    int s = a0 + a1 + a2 + a3;
    int lane = tid & 63;
    int v = s;
#pragma unroll
    for (int off = 1; off < 64; off <<= 1) {
        int u = __shfl_up(v, off, 64);
        if (lane >= off) v += u;
    }
    if (lane == 63) ws[tid >> 6] = v;
    __syncthreads();
    int wof = 0;
    for (int w = 0; w < (tid >> 6); ++w) wof += ws[w];
    int excl = wof + v - s;
    int r0 = excl + a0, r1 = r0 + a1, r2 = r1 + a2, r3 = r2 + a3;
    if (base + 0 < G) cum[base + 0] = r0;
    if (base + 1 < G) cum[base + 1] = r1;
    if (base + 2 < G) cum[base + 2] = r2;
    if (base + 3 < G) cum[base + 3] = r3;
    if (tid == 255) bsum[blockIdx.x] = excl + s;
}

__global__ void k_scan2(int* __restrict__ bsum, int nb) {
    int t = threadIdx.x;  // 64 threads, nb <= 64
    int v = (t < nb) ? bsum[t] : 0;
#pragma unroll
    for (int off = 1; off < 64; off <<= 1) {
        int u = __shfl_up(v, off, 64);
        if (t >= off) v += u;
    }
    if (t < nb) bsum[t] = v;
}

__global__ void k_gid(const int* __restrict__ ids, const int* __restrict__ cum,
                      const int* __restrict__ bsum, int* __restrict__ gid,
                      int* __restrict__ gstart, int* __restrict__ ngr, int n) {
    int i = blockIdx.x * blockDim.x + threadIdx.x;
    if (i >= n) return;
    int v = ids[i];
    int blk = v >> 10;
    int g = cum[v] + (blk ? bsum[blk - 1] : 0) - 1;
    gid[i] = g;
    if (i == 0 || ids[i - 1] != v) gstart[g] = i;
    if (i == n - 1) { gstart[g + 1] = n; *ngr = g + 1; }
}

// E1(bf16) = emb @ W1b^T + b1. 64-row block, LDS-staged, (256,4) occupancy.
__global__ __launch_bounds__(256, 4) void k_egemm(
    const float* __restrict__ emb, const unsigned short* __restrict__ Wf,
    const float* __restrict__ b1, unsigned short* __restrict__ E1b, int G) {
    __shared__ __align__(16) float ebuf[8192];   // 32KB: 64 rows f32
    int tid = threadIdx.x, lane = tid & 63, wid = tid >> 6;
    int p = lane & 15, q = lane >> 4;
    int wr = wid >> 1, wc = wid & 1;
    int row0 = blockIdx.x * 64;

    short8 bfr[4][4];
#pragma unroll
    for (int t = 0; t < 4; ++t)
#pragma unroll
        for (int kk = 0; kk < 4; ++kk)
            bfr[t][kk] = *(const short8*)&Wf[(size_t)((wc * 4 + t) * 4 + kk) * 512 + lane * 8];
    float b1v[4];
#pragma unroll
    for (int t = 0; t < 4; ++t) b1v[t] = b1[wc * 64 + t * 16 + p];

    long long maxb = (long long)G * 512 - 16;
#pragma unroll
    for (int k = 0; k < 8; ++k) {
        int doff = k * 4096 + tid * 16;
        int r = doff >> 9;
        long long s = (long long)(row0 + r) * 512 + (long long)((doff & 511) ^ ((r & 7) << 4));
        s = s < maxb ? s : maxb;
        dma16((const char*)emb + s, (char*)ebuf + doff);
    }
    asm volatile("s_waitcnt vmcnt(0)" ::: "memory");
    __builtin_amdgcn_s_barrier();
    __builtin_amdgcn_sched_barrier(0);

    int sw = (p & 7) << 4;
#pragma unroll
    for (int tt = 0; tt < 2; ++tt) {
        int lr = wr * 32 + tt * 16 + p;
        short8 afr[4];
#pragma unroll
        for (int kk = 0; kk < 4; ++kk) {
            int boff = lr * 512 + kk * 128 + q * 32;
            float4 v0 = lds_rd16(ebuf, boff, sw);
            float4 v1 = lds_rd16(ebuf, boff + 16, sw);
            afr[kk] = pack8(v0, v1);
        }
        f32x4 acc[4];
#pragma unroll
        for (int t = 0; t < 4; ++t) acc[t] = f32x4{0.f, 0.f, 0.f, 0.f};
#pragma unroll
        for (int t = 0; t < 4; ++t)
#pragma unroll
            for (int kk = 0; kk < 4; ++kk)
                acc[t] = __builtin_amdgcn_mfma_f32_16x16x32_bf16(afr[kk], bfr[t][kk], acc[t], 0, 0, 0);
#pragma unroll
        for (int t = 0; t < 4; ++t) {
            int colb = wc * 64 + t * 16 + p;
#pragma unroll
            for (int rg = 0; rg < 4; ++rg) {
                int rr = row0 + wr * 32 + tt * 16 + q * 4 + rg;
                if (rr < G) E1b[(size_t)rr * 128 + colb] = f2bf(acc[t][rg] + b1v[t]);
            }
        }
    }
}

// x_out = x @ W1a^T + E1[gid](bf16)  +  fused group means.
// 32-row block (16.25KB LDS), 64-VGPR cap -> 8 blocks/CU resident (32 waves).
// Scan windows = 16 rows; contained groups -> direct imps write; crossing ->
// atomicAdd into zeroed segsum (finished by k_fix, criterion >>4).
__global__ __launch_bounds__(256, 8) void k_xgemm(
    const float* __restrict__ x, const unsigned short* __restrict__ Wf,
    const int* __restrict__ gid, const unsigned short* __restrict__ E1b,
    const int* __restrict__ ngr,
    float* __restrict__ out, unsigned short* __restrict__ imps,
    float* __restrict__ segsum, int N, int nwg) {
    __shared__ __align__(16) float xbuf[4096];   // 16KB: 32 rows f32
    __shared__ int gids[32];
    int tid = threadIdx.x, lane = tid & 63, wid = tid >> 6;
    int p = lane & 15, q = lane >> 4;
    int wr = wid >> 1, wc = wid & 1;
    // bijective XCD swizzle (m204)
    int orig = blockIdx.x;
    int qq = nwg >> 3, rr8 = nwg & 7;
    int xcd = orig & 7, idx = orig >> 3;
    int bid = (xcd < rr8 ? xcd * (qq + 1) : rr8 * (qq + 1) + (xcd - rr8) * qq) + idx;
    int row0 = bid * 32;

    short8 bfr[4][4];
#pragma unroll
    for (int t = 0; t < 4; ++t)
#pragma unroll
        for (int kk = 0; kk < 4; ++kk)
            bfr[t][kk] = *(const short8*)&Wf[(size_t)((wc * 4 + t) * 4 + kk) * 512 + lane * 8];

    int gt = gid[min(row0 + wr * 16 + p, N - 1)];

    // scan geometry + edge loads (issued early, hidden under DMA)
    int c = tid & 127, h = tid >> 7;
    int lo = row0 + h * 16;
    int hi = min(lo + 16, N);
    int gbefore = -1, gafter = -1;
    if (lo > 0 && lo < N) gbefore = gid[lo - 1];
    if (hi < N) gafter = gid[hi];

    long long maxb = (long long)N * 512 - 16;
#pragma unroll
    for (int k = 0; k < 4; ++k) {
        int doff = k * 4096 + tid * 16;
        int r = doff >> 9;
        long long s = (long long)(row0 + r) * 512 + (long long)((doff & 511) ^ ((r & 7) << 4));
        s = s < maxb ? s : maxb;
        dma16((const char*)x + s, (char*)xbuf + doff);
    }
    if (wc == 0) gids[wr * 16 + p] = gt;   // rows wr*16 .. wr*16+15
    asm volatile("s_waitcnt vmcnt(0) lgkmcnt(0)" ::: "memory");
    __builtin_amdgcn_s_barrier();
    __builtin_amdgcn_sched_barrier(0);

    int sw = (p & 7) << 4;
    {
        int lr = wr * 16 + p;
        short8 afr[4];
#pragma unroll
        for (int kk = 0; kk < 4; ++kk) {
            int boff = lr * 512 + kk * 128 + q * 32;
            float4 v0 = lds_rd16(xbuf, boff, sw);
            float4 v1 = lds_rd16(xbuf, boff + 16, sw);
            afr[kk] = pack8(v0, v1);
        }
        int g4[4];
#pragma unroll
        for (int rg = 0; rg < 4; ++rg) g4[rg] = __shfl(gt, q * 4 + rg);
        float ev[4][4];
#pragma unroll
        for (int t = 0; t < 4; ++t) {
            int colb = wc * 64 + t * 16 + p;
#pragma unroll
            for (int rg = 0; rg < 4; ++rg)
                ev[t][rg] = bf2f(E1b[(size_t)g4[rg] * 128 + colb]);
        }
        f32x4 acc[4];
#pragma unroll
        for (int t = 0; t < 4; ++t) acc[t] = f32x4{0.f, 0.f, 0.f, 0.f};
#pragma unroll
        for (int t = 0; t < 4; ++t)
#pragma unroll
            for (int kk = 0; kk < 4; ++kk)
                acc[t] = __builtin_amdgcn_mfma_f32_16x16x32_bf16(afr[kk], bfr[t][kk], acc[t], 0, 0, 0);
#pragma unroll
        for (int t = 0; t < 4; ++t) {
            int colb = wc * 64 + t * 16 + p;
#pragma unroll
            for (int rg = 0; rg < 4; ++rg) {
                int rr = row0 + wr * 16 + q * 4 + rg;
                if (rr < N) out[(size_t)rr * 128 + colb] = acc[t][rg] + ev[t][rg];
            }
        }
    }

    // ---- fused group means from LDS (batched reads; 16-row window) ----
    if (lo < N) {
        int nwin = hi - lo;                 // 1..16
        int gbase = h * 16;
        int ng = *ngr;
        int gcur = gids[gbase];
        bool open_left = (gcur == gbefore);
        int rs = lo;
        float s = 0.f;
        for (int bb = 0; bb < nwin; bb += 8) {
            float v[8];
            int gn[8];
#pragma unroll
            for (int j = 0; j < 8; ++j) {
                int rr = bb + j; rr = rr < nwin - 1 ? rr : nwin - 1;
                int lrr = gbase + rr;
                v[j] = *(const float*)((const char*)xbuf + lrr * 512 + ((c * 4) ^ ((lrr & 7) << 4)));
                int rn = bb + j + 1; rn = rn < nwin - 1 ? rn : nwin - 1;
                gn[j] = gids[gbase + rn];
            }
#pragma unroll
            for (int j = 0; j < 8; ++j) {
                int r = bb + j;
                if (r < nwin) {
                    s += v[j];
                    bool at_end = (r + 1 >= nwin);
                    int gnext = at_end ? gafter : gn[j];
                    if (at_end || gnext != gcur) {
                        bool open_right = at_end && (gafter == gcur);
                        if (!open_left && !open_right) {
                            if (gcur < ng - 1)
                                imps[(size_t)gcur * 128 + c] = f2bf(s / (float)(lo + r + 1 - rs));
                        } else {
                            atomicAdd(&segsum[(size_t)gcur * 128 + c], s);
                        }
                        s = 0.f; rs = lo + r + 1; gcur = gnext; open_left = false;
                    }
                }
            }
        }
    }
}

// Finish crossing groups (segsum/n) and emb-copy for unwritten tail groups.
// Containment window = 16 rows (must mirror k_xgemm).
__global__ __launch_bounds__(256) void k_fix(
    const float* __restrict__ segsum, const float* __restrict__ emb,
    const int* __restrict__ gstart, const int* __restrict__ ngr,
    unsigned short* __restrict__ imps, int G) {
    int g = blockIdx.x * 4 + (threadIdx.x >> 6);
    int lane = threadIdx.x & 63;
    if (g >= G) return;
    int ng = *ngr;
    float2 m;
    if (g < ng - 1) {
        int a = gstart[g], b = gstart[g + 1];
        if ((a >> 4) == ((b - 1) >> 4)) return;  // contained: imps already written
        float inv = 1.0f / (float)(b - a);
        float2 s = *(const float2*)&segsum[(size_t)g * 128 + lane * 2];
        m.x = s.x * inv; m.y = s.y * inv;
    } else {
        m = *(const float2*)&emb[(size_t)g * 128 + lane * 2];
    }
    unsigned int pk = (unsigned int)f2bf(m.x) | ((unsigned int)f2bf(m.y) << 16);
    ((unsigned int*)imps)[(size_t)g * 64 + lane] = pk;
}

// imputed_out = emb @ W2a^T + imps @ W2b^T + b2. 64-row block, LDS-staged.
__global__ __launch_bounds__(256, 2) void k_igemm(
    const float* __restrict__ emb, const unsigned short* __restrict__ imps,
    const unsigned short* __restrict__ Waf, const unsigned short* __restrict__ Wbf,
    const float* __restrict__ b2, float* __restrict__ out2, int G) {
    __shared__ __align__(16) float ebuf[8192];            // 32KB: 64 rows f32
    __shared__ __align__(16) unsigned short ibuf[8192];   // 16KB: 64 rows bf16
    int tid = threadIdx.x, lane = tid & 63, wid = tid >> 6;
    int p = lane & 15, q = lane >> 4;
    int wr = wid >> 1, wc = wid & 1;
    int row0 = blockIdx.x * 64;

    short8 bfrA[4][4], bfrB[4][4];
#pragma unroll
    for (int t = 0; t < 4; ++t)
#pragma unroll
        for (int kk = 0; kk < 4; ++kk) {
            bfrA[t][kk] = *(const short8*)&Waf[(size_t)((wc * 4 + t) * 4 + kk) * 512 + lane * 8];
            bfrB[t][kk] = *(const short8*)&Wbf[(size_t)((wc * 4 + t) * 4 + kk) * 512 + lane * 8];
        }
    float b2v[4];
#pragma unroll
    for (int t = 0; t < 4; ++t) b2v[t] = b2[wc * 64 + t * 16 + p];

    long long maxe = (long long)G * 512 - 16;
    long long maxi = (long long)G * 256 - 16;
#pragma unroll
    for (int k = 0; k < 8; ++k) {
        int doff = k * 4096 + tid * 16;
        int r = doff >> 9;
        long long s = (long long)(row0 + r) * 512 + (long long)((doff & 511) ^ ((r & 7) << 4));
        s = s < maxe ? s : maxe;
        dma16((const char*)emb + s, (char*)ebuf + doff);
    }
#pragma unroll
    for (int k = 0; k < 4; ++k) {
        int doff = k * 4096 + tid * 16;
        int r = doff >> 8;
        long long s = (long long)(row0 + r) * 256 + (long long)((doff & 255) ^ ((r & 7) << 4));
        s = s < maxi ? s : maxi;
        dma16((const char*)imps + s, (char*)ibuf + doff);
    }
    asm volatile("s_waitcnt vmcnt(0)" ::: "memory");
    __builtin_amdgcn_s_barrier();
    __builtin_amdgcn_sched_barrier(0);

    int sw = (p & 7) << 4;
#pragma unroll
    for (int tt = 0; tt < 2; ++tt) {
        int lr = wr * 32 + tt * 16 + p;
        short8 ae[4], ia[4];
#pragma unroll
        for (int kk = 0; kk < 4; ++kk) {
            int boff = lr * 512 + kk * 128 + q * 32;
            float4 v0 = lds_rd16(ebuf, boff, sw);
            float4 v1 = lds_rd16(ebuf, boff + 16, sw);
            ae[kk] = pack8(v0, v1);
            int boff2 = lr * 256 + ((kk * 64 + q * 16) ^ sw);
            ia[kk] = *(const short8*)((const char*)ibuf + boff2);
        }
        f32x4 acc[4];
#pragma unroll
        for (int t = 0; t < 4; ++t) acc[t] = f32x4{0.f, 0.f, 0.f, 0.f};
#pragma unroll
        for (int kk = 0; kk < 4; ++kk)
#pragma unroll
            for (int t = 0; t < 4; ++t) {
                acc[t] = __builtin_amdgcn_mfma_f32_16x16x32_bf16(ae[kk], bfrA[t][kk], acc[t], 0, 0, 0);
                acc[t] = __builtin_amdgcn_mfma_f32_16x16x32_bf16(ia[kk], bfrB[t][kk], acc[t], 0, 0, 0);
            }
#pragma unroll
        for (int t = 0; t < 4; ++t) {
            int colb = wc * 64 + t * 16 + p;
#pragma unroll
            for (int rg = 0; rg < 4; ++rg) {
                int rr = row0 + wr * 32 + tt * 16 + q * 4 + rg;
                if (rr < G) out2[(size_t)rr * 128 + colb] = acc[t][rg] + b2v[t];
            }
        }
    }
}

extern "C" void kernel_launch(void* const* d_in, const int* in_sizes, int n_in,
                              void* d_out, int out_size, void* d_ws, size_t ws_size,
                              hipStream_t stream) {
    const float* x   = (const float*)d_in[0];
    const float* emb = (const float*)d_in[1];
    const float* W1  = (const float*)d_in[2];
    const float* b1  = (const float*)d_in[3];
    const float* W2  = (const float*)d_in[4];
    const float* b2  = (const float*)d_in[5];
    const int*   ids = (const int*)d_in[6];
    const int H = 128;
    const int N = in_sizes[6];
    const int G = in_sizes[1] / H;

    float* out  = (float*)d_out;
    float* out2 = out + (size_t)N * H;

    char* ws = (char*)d_ws;
    size_t off = 0;
    float* segsum = (float*)(ws + off); off += (size_t)G * H * 4;
    int*   cum    = (int*)(ws + off);   off += (size_t)G * 4;
    size_t zbytes = off;                              // zero region: segsum + cum
    off = (off + 255) & ~(size_t)255;
    int* bsum   = (int*)(ws + off); off += 64 * 4;          off = (off + 255) & ~(size_t)255;
    int* gid    = (int*)(ws + off); off += (size_t)N * 4;   off = (off + 255) & ~(size_t)255;
    int* gstart = (int*)(ws + off); off += (size_t)(G + 1) * 4; off = (off + 255) & ~(size_t)255;
    int* ngr    = (int*)(ws + off); off += 256;
    unsigned short* W1af = (unsigned short*)(ws + off); off += (size_t)H * H * 2;
    unsigned short* W1bf = (unsigned short*)(ws + off); off += (size_t)H * H * 2;
    unsigned short* W2af = (unsigned short*)(ws + off); off += (size_t)H * H * 2;
    unsigned short* W2bf = (unsigned short*)(ws + off); off += (size_t)H * H * 2;
    unsigned short* imps = (unsigned short*)(ws + off); off += (size_t)G * H * 2;
    unsigned short* E1b  = (unsigned short*)(ws + off); off += (size_t)G * H * 2;

    int n16 = (int)((zbytes + 15) / 16);
    int nb = (G + 1023) >> 10;
    int nwgX = (N + 31) >> 5;
    int nwgE = (G + 63) >> 6;
    int nwgI = (G + 63) >> 6;
    k_zero<<<(n16 + 255) / 256, 256, 0, stream>>>((uint4*)ws, n16);
    k_convw<<<32, 256, 0, stream>>>(W1, W2, W1af, W1bf, W2af, W2bf);
    k_mark<<<(N + 255) / 256, 256, 0, stream>>>(ids, cum, N);
    k_scan1<<<nb, 256, 0, stream>>>(cum, bsum, G);
    k_scan2<<<1, 64, 0, stream>>>(bsum, nb);
    k_gid<<<(N + 255) / 256, 256, 0, stream>>>(ids, cum, bsum, gid, gstart, ngr, N);
    k_egemm<<<nwgE, 256, 0, stream>>>(emb, W1bf, b1, E1b, G);
    k_xgemm<<<nwgX, 256, 0, stream>>>(x, W1af, gid, E1b, ngr, out, imps, segsum, N, nwgX);
    k_fix<<<(G + 3) / 4, 256, 0, stream>>>(segsum, emb, gstart, ngr, imps, G);
    k_igemm<<<nwgI, 256, 0, stream>>>(emb, imps, W2af, W2bf, b2, out2, G);
}

// Round 16
// 248.859 us; speedup vs baseline: 1.5566x; 1.5566x over previous
//
#include <hip/hip_runtime.h>

typedef __attribute__((ext_vector_type(8))) short short8;
typedef __attribute__((ext_vector_type(4))) float f32x4;

static __device__ __forceinline__ unsigned short f2bf(float f) {
    union { float f; unsigned int u; } v; v.f = f;
    unsigned int r = v.u + 0x7fffu + ((v.u >> 16) & 1u);  // RNE
    return (unsigned short)(r >> 16);
}

static __device__ __forceinline__ float bf2f(unsigned short b) {
    union { unsigned int u; float f; } v; v.u = (unsigned int)b << 16; return v.f;
}

// HW packed f32->bf16 (RNE): one instruction per 2 elements.
static __device__ __forceinline__ short8 pack8(float4 a, float4 b) {
    union { unsigned int u[4]; short8 s; } r;
    asm("v_cvt_pk_bf16_f32 %0, %1, %2" : "=v"(r.u[0]) : "v"(a.x), "v"(a.y));
    asm("v_cvt_pk_bf16_f32 %0, %1, %2" : "=v"(r.u[1]) : "v"(a.z), "v"(a.w));
    asm("v_cvt_pk_bf16_f32 %0, %1, %2" : "=v"(r.u[2]) : "v"(b.x), "v"(b.y));
    asm("v_cvt_pk_bf16_f32 %0, %1, %2" : "=v"(r.u[3]) : "v"(b.z), "v"(b.w));
    return r.s;
}

static __device__ __forceinline__ void dma16(const void* g, void* l) {
    __builtin_amdgcn_global_load_lds(
        (const __attribute__((address_space(1))) unsigned int*)g,
        (__attribute__((address_space(3))) unsigned int*)l, 16, 0, 0);
}

static __device__ __forceinline__ float4 lds_rd16(const float* buf, int boff, int sw) {
    return *(const float4*)((const char*)buf + (boff ^ sw));
}

__global__ void k_zero(uint4* p, int n16) {
    int i = blockIdx.x * blockDim.x + threadIdx.x;
    if (i < n16) p[i] = uint4{0u, 0u, 0u, 0u};
}

// Pack W1,W2 (f32 [128][256]) into 4 fragment-ordered bf16 arrays.
__global__ void k_convw(const float* __restrict__ W1, const float* __restrict__ W2,
                        unsigned short* W1af, unsigned short* W1bf,
                        unsigned short* W2af, unsigned short* W2bf) {
    int T = blockIdx.x * 256 + threadIdx.x;   // 8192 total
    int mat = T >> 11;
    int rem = T & 2047;
    int f = rem >> 6, lane = rem & 63;
    int wc = f >> 4, t = (f >> 2) & 3, kk = f & 3;
    int p = lane & 15, q = lane >> 4;
    int row = wc * 64 + t * 16 + p;
    int col = (mat & 1) * 128 + kk * 32 + q * 8;
    const float* src = (mat < 2 ? W1 : W2) + row * 256 + col;
    unsigned short* dst = (mat == 0 ? W1af : mat == 1 ? W1bf : mat == 2 ? W2af : W2bf);
    short8 v;
#pragma unroll
    for (int j = 0; j < 8; ++j) v[j] = (short)f2bf(src[j]);
    *(short8*)&dst[(size_t)f * 512 + lane * 8] = v;
}

__global__ void k_mark(const int* __restrict__ ids, int* __restrict__ cum, int n) {
    int i = blockIdx.x * blockDim.x + threadIdx.x;
    if (i < n) cum[ids[i]] = 1;
}

// 2-level scan: per-block inclusive scan of 1024 ints + block sums
__global__ __launch_bounds__(256) void k_scan1(int* __restrict__ cum, int* __restrict__ bsum, int G) {
    __shared__ int ws[4];
    int tid = threadIdx.x;
    int base = blockIdx.x * 1024 + tid * 4;
    int a0 = 0, a1 = 0, a2 = 0, a3 = 0;
    if (base + 0 < G) a0 = cum[base + 0];
    if (base + 1 < G) a1 = cum[base + 1];
    if (base + 2 < G) a2 = cum[base + 2];
    if (base + 3 < G) a3 = cum[base + 3];
    int s = a0 + a1 + a2 + a3;
    int lane = tid & 63;
    int v = s;
#pragma unroll
    for (int off = 1; off < 64; off <<= 1) {
        int u = __shfl_up(v, off, 64);
        if (lane >= off) v += u;
    }
    if (lane == 63) ws[tid >> 6] = v;
    __syncthreads();
    int wof = 0;
    for (int w = 0; w < (tid >> 6); ++w) wof += ws[w];
    int excl = wof + v - s;
    int r0 = excl + a0, r1 = r0 + a1, r2 = r1 + a2, r3 = r2 + a3;
    if (base + 0 < G) cum[base + 0] = r0;
    if (base + 1 < G) cum[base + 1] = r1;
    if (base + 2 < G) cum[base + 2] = r2;
    if (base + 3 < G) cum[base + 3] = r3;
    if (tid == 255) bsum[blockIdx.x] = excl + s;
}

__global__ void k_scan2(int* __restrict__ bsum, int nb) {
    int t = threadIdx.x;  // 64 threads, nb <= 64
    int v = (t < nb) ? bsum[t] : 0;
#pragma unroll
    for (int off = 1; off < 64; off <<= 1) {
        int u = __shfl_up(v, off, 64);
        if (t >= off) v += u;
    }
    if (t < nb) bsum[t] = v;
}

__global__ void k_gid(const int* __restrict__ ids, const int* __restrict__ cum,
                      const int* __restrict__ bsum, int* __restrict__ gid,
                      int* __restrict__ gstart, int* __restrict__ ngr, int n) {
    int i = blockIdx.x * blockDim.x + threadIdx.x;
    if (i >= n) return;
    int v = ids[i];
    int blk = v >> 10;
    int g = cum[v] + (blk ? bsum[blk - 1] : 0) - 1;
    gid[i] = g;
    if (i == 0 || ids[i - 1] != v) gstart[g] = i;
    if (i == n - 1) { gstart[g + 1] = n; *ngr = g + 1; }
}

// E1(bf16) = emb @ W1b^T + b1. 64-row block, LDS-staged, (256,4) occupancy.
__global__ __launch_bounds__(256, 4) void k_egemm(
    const float* __restrict__ emb, const unsigned short* __restrict__ Wf,
    const float* __restrict__ b1, unsigned short* __restrict__ E1b, int G) {
    __shared__ __align__(16) float ebuf[8192];   // 32KB: 64 rows f32
    int tid = threadIdx.x, lane = tid & 63, wid = tid >> 6;
    int p = lane & 15, q = lane >> 4;
    int wr = wid >> 1, wc = wid & 1;
    int row0 = blockIdx.x * 64;

    short8 bfr[4][4];
#pragma unroll
    for (int t = 0; t < 4; ++t)
#pragma unroll
        for (int kk = 0; kk < 4; ++kk)
            bfr[t][kk] = *(const short8*)&Wf[(size_t)((wc * 4 + t) * 4 + kk) * 512 + lane * 8];
    float b1v[4];
#pragma unroll
    for (int t = 0; t < 4; ++t) b1v[t] = b1[wc * 64 + t * 16 + p];

    long long maxb = (long long)G * 512 - 16;
#pragma unroll
    for (int k = 0; k < 8; ++k) {
        int doff = k * 4096 + tid * 16;
        int r = doff >> 9;
        long long s = (long long)(row0 + r) * 512 + (long long)((doff & 511) ^ ((r & 7) << 4));
        s = s < maxb ? s : maxb;
        dma16((const char*)emb + s, (char*)ebuf + doff);
    }
    asm volatile("s_waitcnt vmcnt(0)" ::: "memory");
    __builtin_amdgcn_s_barrier();
    __builtin_amdgcn_sched_barrier(0);

    int sw = (p & 7) << 4;
#pragma unroll
    for (int tt = 0; tt < 2; ++tt) {
        int lr = wr * 32 + tt * 16 + p;
        short8 afr[4];
#pragma unroll
        for (int kk = 0; kk < 4; ++kk) {
            int boff = lr * 512 + kk * 128 + q * 32;
            float4 v0 = lds_rd16(ebuf, boff, sw);
            float4 v1 = lds_rd16(ebuf, boff + 16, sw);
            afr[kk] = pack8(v0, v1);
        }
        f32x4 acc[4];
#pragma unroll
        for (int t = 0; t < 4; ++t) acc[t] = f32x4{0.f, 0.f, 0.f, 0.f};
#pragma unroll
        for (int t = 0; t < 4; ++t)
#pragma unroll
            for (int kk = 0; kk < 4; ++kk)
                acc[t] = __builtin_amdgcn_mfma_f32_16x16x32_bf16(afr[kk], bfr[t][kk], acc[t], 0, 0, 0);
#pragma unroll
        for (int t = 0; t < 4; ++t) {
            int colb = wc * 64 + t * 16 + p;
#pragma unroll
            for (int rg = 0; rg < 4; ++rg) {
                int rr = row0 + wr * 32 + tt * 16 + q * 4 + rg;
                if (rr < G) E1b[(size_t)rr * 128 + colb] = f2bf(acc[t][rg] + b1v[t]);
            }
        }
    }
}

// x_out = x @ W1a^T + E1[gid](bf16)  +  fused group means.
// Round-14 structure (64-row block, single vmcnt(0)+barrier, 4 blocks/CU) with
// E1b gathers HOISTED above the drain: their addresses depend only on gt (not
// LDS), so they issue during the DMA wait and land with the drain.
__global__ __launch_bounds__(256, 4) void k_xgemm(
    const float* __restrict__ x, const unsigned short* __restrict__ Wf,
    const int* __restrict__ gid, const unsigned short* __restrict__ E1b,
    const int* __restrict__ ngr,
    float* __restrict__ out, unsigned short* __restrict__ imps,
    float* __restrict__ segsum, int N, int nwg) {
    __shared__ __align__(16) float xbuf[8192];   // 32KB: 64 rows f32
    __shared__ int gids[64];
    int tid = threadIdx.x, lane = tid & 63, wid = tid >> 6;
    int p = lane & 15, q = lane >> 4;
    int wr = wid >> 1, wc = wid & 1;
    // bijective XCD swizzle (m204)
    int orig = blockIdx.x;
    int qq = nwg >> 3, rr8 = nwg & 7;
    int xcd = orig & 7, idx = orig >> 3;
    int bid = (xcd < rr8 ? xcd * (qq + 1) : rr8 * (qq + 1) + (xcd - rr8) * qq) + idx;
    int row0 = bid * 64;

    short8 bfr[4][4];
#pragma unroll
    for (int t = 0; t < 4; ++t)
#pragma unroll
        for (int kk = 0; kk < 4; ++kk)
            bfr[t][kk] = *(const short8*)&Wf[(size_t)((wc * 4 + t) * 4 + kk) * 512 + lane * 8];

    int gt[2];
#pragma unroll
    for (int tt = 0; tt < 2; ++tt)
        gt[tt] = gid[min(row0 + wr * 32 + tt * 16 + p, N - 1)];

    // scan geometry + edge loads (issued early, hidden under DMA)
    int c = tid & 127, h = tid >> 7;
    int lo = row0 + h * 32;
    int hi = min(lo + 32, N);
    int gbefore = -1, gafter = -1;
    if (lo > 0 && lo < N) gbefore = gid[lo - 1];
    if (hi < N) gafter = gid[hi];

    long long maxb = (long long)N * 512 - 16;
#pragma unroll
    for (int k = 0; k < 8; ++k) {
        int doff = k * 4096 + tid * 16;
        int r = doff >> 9;
        long long s = (long long)(row0 + r) * 512 + (long long)((doff & 511) ^ ((r & 7) << 4));
        s = s < maxb ? s : maxb;
        dma16((const char*)x + s, (char*)xbuf + doff);
    }
    if (wc == 0) {   // stage this block's gids into LDS (rows wr*32 .. wr*32+31)
#pragma unroll
        for (int tt = 0; tt < 2; ++tt)
            gids[wr * 32 + tt * 16 + p] = gt[tt];
    }

    // HOISTED E1b gather: addresses from gt only; loads overlap the DMA wait.
    float ev[2][4][4];
#pragma unroll
    for (int tt = 0; tt < 2; ++tt) {
        int g4[4];
#pragma unroll
        for (int rg = 0; rg < 4; ++rg) g4[rg] = __shfl(gt[tt], q * 4 + rg);
#pragma unroll
        for (int t = 0; t < 4; ++t) {
            int colb = wc * 64 + t * 16 + p;
#pragma unroll
            for (int rg = 0; rg < 4; ++rg)
                ev[tt][t][rg] = bf2f(E1b[(size_t)g4[rg] * 128 + colb]);
        }
    }

    asm volatile("s_waitcnt vmcnt(0) lgkmcnt(0)" ::: "memory");
    __builtin_amdgcn_s_barrier();
    __builtin_amdgcn_sched_barrier(0);

    int sw = (p & 7) << 4;
#pragma unroll
    for (int tt = 0; tt < 2; ++tt) {
        int lr = wr * 32 + tt * 16 + p;
        short8 afr[4];
#pragma unroll
        for (int kk = 0; kk < 4; ++kk) {
            int boff = lr * 512 + kk * 128 + q * 32;
            float4 v0 = lds_rd16(xbuf, boff, sw);
            float4 v1 = lds_rd16(xbuf, boff + 16, sw);
            afr[kk] = pack8(v0, v1);
        }
        f32x4 acc[4];
#pragma unroll
        for (int t = 0; t < 4; ++t) acc[t] = f32x4{0.f, 0.f, 0.f, 0.f};
#pragma unroll
        for (int t = 0; t < 4; ++t)
#pragma unroll
            for (int kk = 0; kk < 4; ++kk)
                acc[t] = __builtin_amdgcn_mfma_f32_16x16x32_bf16(afr[kk], bfr[t][kk], acc[t], 0, 0, 0);
#pragma unroll
        for (int t = 0; t < 4; ++t) {
            int colb = wc * 64 + t * 16 + p;
#pragma unroll
            for (int rg = 0; rg < 4; ++rg) {
                int rr = row0 + wr * 32 + tt * 16 + q * 4 + rg;
                if (rr < N) out[(size_t)rr * 128 + colb] = acc[t][rg] + ev[tt][t][rg];
            }
        }
    }

    // ---- fused group means from LDS (batched reads; 32-row window) ----
    if (lo < N) {
        int nwin = hi - lo;                 // 1..32
        int gbase = h * 32;
        int ng = *ngr;
        int gcur = gids[gbase];
        bool open_left = (gcur == gbefore);
        int rs = lo;
        float s = 0.f;
        for (int bb = 0; bb < nwin; bb += 8) {
            float v[8];
            int gn[8];
#pragma unroll
            for (int j = 0; j < 8; ++j) {
                int rr = bb + j; rr = rr < nwin - 1 ? rr : nwin - 1;
                int lrr = gbase + rr;
                v[j] = *(const float*)((const char*)xbuf + lrr * 512 + ((c * 4) ^ ((lrr & 7) << 4)));
                int rn = bb + j + 1; rn = rn < nwin - 1 ? rn : nwin - 1;
                gn[j] = gids[gbase + rn];
            }
#pragma unroll
            for (int j = 0; j < 8; ++j) {
                int r = bb + j;
                if (r < nwin) {
                    s += v[j];
                    bool at_end = (r + 1 >= nwin);
                    int gnext = at_end ? gafter : gn[j];
                    if (at_end || gnext != gcur) {
                        bool open_right = at_end && (gafter == gcur);
                        if (!open_left && !open_right) {
                            if (gcur < ng - 1)
                                imps[(size_t)gcur * 128 + c] = f2bf(s / (float)(lo + r + 1 - rs));
                        } else {
                            atomicAdd(&segsum[(size_t)gcur * 128 + c], s);
                        }
                        s = 0.f; rs = lo + r + 1; gcur = gnext; open_left = false;
                    }
                }
            }
        }
    }
}

// Finish crossing groups (segsum/n) and emb-copy for unwritten tail groups.
// Containment window = 32 rows (must mirror k_xgemm).
__global__ __launch_bounds__(256) void k_fix(
    const float* __restrict__ segsum, const float* __restrict__ emb,
    const int* __restrict__ gstart, const int* __restrict__ ngr,
    unsigned short* __restrict__ imps, int G) {
    int g = blockIdx.x * 4 + (threadIdx.x >> 6);
    int lane = threadIdx.x & 63;
    if (g >= G) return;
    int ng = *ngr;
    float2 m;
    if (g < ng - 1) {
        int a = gstart[g], b = gstart[g + 1];
        if ((a >> 5) == ((b - 1) >> 5)) return;  // contained: imps already written
        float inv = 1.0f / (float)(b - a);
        float2 s = *(const float2*)&segsum[(size_t)g * 128 + lane * 2];
        m.x = s.x * inv; m.y = s.y * inv;
    } else {
        m = *(const float2*)&emb[(size_t)g * 128 + lane * 2];
    }
    unsigned int pk = (unsigned int)f2bf(m.x) | ((unsigned int)f2bf(m.y) << 16);
    ((unsigned int*)imps)[(size_t)g * 64 + lane] = pk;
}

// imputed_out = emb @ W2a^T + imps @ W2b^T + b2. 64-row block, LDS-staged.
__global__ __launch_bounds__(256, 2) void k_igemm(
    const float* __restrict__ emb, const unsigned short* __restrict__ imps,
    const unsigned short* __restrict__ Waf, const unsigned short* __restrict__ Wbf,
    const float* __restrict__ b2, float* __restrict__ out2, int G) {
    __shared__ __align__(16) float ebuf[8192];            // 32KB: 64 rows f32
    __shared__ __align__(16) unsigned short ibuf[8192];   // 16KB: 64 rows bf16
    int tid = threadIdx.x, lane = tid & 63, wid = tid >> 6;
    int p = lane & 15, q = lane >> 4;
    int wr = wid >> 1, wc = wid & 1;
    int row0 = blockIdx.x * 64;

    short8 bfrA[4][4], bfrB[4][4];
#pragma unroll
    for (int t = 0; t < 4; ++t)
#pragma unroll
        for (int kk = 0; kk < 4; ++kk) {
            bfrA[t][kk] = *(const short8*)&Waf[(size_t)((wc * 4 + t) * 4 + kk) * 512 + lane * 8];
            bfrB[t][kk] = *(const short8*)&Wbf[(size_t)((wc * 4 + t) * 4 + kk) * 512 + lane * 8];
        }
    float b2v[4];
#pragma unroll
    for (int t = 0; t < 4; ++t) b2v[t] = b2[wc * 64 + t * 16 + p];

    long long maxe = (long long)G * 512 - 16;
    long long maxi = (long long)G * 256 - 16;
#pragma unroll
    for (int k = 0; k < 8; ++k) {
        int doff = k * 4096 + tid * 16;
        int r = doff >> 9;
        long long s = (long long)(row0 + r) * 512 + (long long)((doff & 511) ^ ((r & 7) << 4));
        s = s < maxe ? s : maxe;
        dma16((const char*)emb + s, (char*)ebuf + doff);
    }
#pragma unroll
    for (int k = 0; k < 4; ++k) {
        int doff = k * 4096 + tid * 16;
        int r = doff >> 8;
        long long s = (long long)(row0 + r) * 256 + (long long)((doff & 255) ^ ((r & 7) << 4));
        s = s < maxi ? s : maxi;
        dma16((const char*)imps + s, (char*)ibuf + doff);
    }
    asm volatile("s_waitcnt vmcnt(0)" ::: "memory");
    __builtin_amdgcn_s_barrier();
    __builtin_amdgcn_sched_barrier(0);

    int sw = (p & 7) << 4;
#pragma unroll
    for (int tt = 0; tt < 2; ++tt) {
        int lr = wr * 32 + tt * 16 + p;
        short8 ae[4], ia[4];
#pragma unroll
        for (int kk = 0; kk < 4; ++kk) {
            int boff = lr * 512 + kk * 128 + q * 32;
            float4 v0 = lds_rd16(ebuf, boff, sw);
            float4 v1 = lds_rd16(ebuf, boff + 16, sw);
            ae[kk] = pack8(v0, v1);
            int boff2 = lr * 256 + ((kk * 64 + q * 16) ^ sw);
            ia[kk] = *(const short8*)((const char*)ibuf + boff2);
        }
        f32x4 acc[4];
#pragma unroll
        for (int t = 0; t < 4; ++t) acc[t] = f32x4{0.f, 0.f, 0.f, 0.f};
#pragma unroll
        for (int kk = 0; kk < 4; ++kk)
#pragma unroll
            for (int t = 0; t < 4; ++t) {
                acc[t] = __builtin_amdgcn_mfma_f32_16x16x32_bf16(ae[kk], bfrA[t][kk], acc[t], 0, 0, 0);
                acc[t] = __builtin_amdgcn_mfma_f32_16x16x32_bf16(ia[kk], bfrB[t][kk], acc[t], 0, 0, 0);
            }
#pragma unroll
        for (int t = 0; t < 4; ++t) {
            int colb = wc * 64 + t * 16 + p;
#pragma unroll
            for (int rg = 0; rg < 4; ++rg) {
                int rr = row0 + wr * 32 + tt * 16 + q * 4 + rg;
                if (rr < G) out2[(size_t)rr * 128 + colb] = acc[t][rg] + b2v[t];
            }
        }
    }
}

extern "C" void kernel_launch(void* const* d_in, const int* in_sizes, int n_in,
                              void* d_out, int out_size, void* d_ws, size_t ws_size,
                              hipStream_t stream) {
    const float* x   = (const float*)d_in[0];
    const float* emb = (const float*)d_in[1];
    const float* W1  = (const float*)d_in[2];
    const float* b1  = (const float*)d_in[3];
    const float* W2  = (const float*)d_in[4];
    const float* b2  = (const float*)d_in[5];
    const int*   ids = (const int*)d_in[6];
    const int H = 128;
    const int N = in_sizes[6];
    const int G = in_sizes[1] / H;

    float* out  = (float*)d_out;
    float* out2 = out + (size_t)N * H;

    char* ws = (char*)d_ws;
    size_t off = 0;
    float* segsum = (float*)(ws + off); off += (size_t)G * H * 4;
    int*   cum    = (int*)(ws + off);   off += (size_t)G * 4;
    size_t zbytes = off;                              // zero region: segsum + cum
    off = (off + 255) & ~(size_t)255;
    int* bsum   = (int*)(ws + off); off += 64 * 4;          off = (off + 255) & ~(size_t)255;
    int* gid    = (int*)(ws + off); off += (size_t)N * 4;   off = (off + 255) & ~(size_t)255;
    int* gstart = (int*)(ws + off); off += (size_t)(G + 1) * 4; off = (off + 255) & ~(size_t)255;
    int* ngr    = (int*)(ws + off); off += 256;
    unsigned short* W1af = (unsigned short*)(ws + off); off += (size_t)H * H * 2;
    unsigned short* W1bf = (unsigned short*)(ws + off); off += (size_t)H * H * 2;
    unsigned short* W2af = (unsigned short*)(ws + off); off += (size_t)H * H * 2;
    unsigned short* W2bf = (unsigned short*)(ws + off); off += (size_t)H * H * 2;
    unsigned short* imps = (unsigned short*)(ws + off); off += (size_t)G * H * 2;
    unsigned short* E1b  = (unsigned short*)(ws + off); off += (size_t)G * H * 2;

    int n16 = (int)((zbytes + 15) / 16);
    int nb = (G + 1023) >> 10;
    int nwgX = (N + 63) >> 6;
    int nwgE = (G + 63) >> 6;
    int nwgI = (G + 63) >> 6;
    k_zero<<<(n16 + 255) / 256, 256, 0, stream>>>((uint4*)ws, n16);
    k_convw<<<32, 256, 0, stream>>>(W1, W2, W1af, W1bf, W2af, W2bf);
    k_mark<<<(N + 255) / 256, 256, 0, stream>>>(ids, cum, N);
    k_scan1<<<nb, 256, 0, stream>>>(cum, bsum, G);
    k_scan2<<<1, 64, 0, stream>>>(bsum, nb);
    k_gid<<<(N + 255) / 256, 256, 0, stream>>>(ids, cum, bsum, gid, gstart, ngr, N);
    k_egemm<<<nwgE, 256, 0, stream>>>(emb, W1bf, b1, E1b, G);
    k_xgemm<<<nwgX, 256, 0, stream>>>(x, W1af, gid, E1b, ngr, out, imps, segsum, N, nwgX);
    k_fix<<<(G + 3) / 4, 256, 0, stream>>>(segsum, emb, gstart, ngr, imps, G);
    k_igemm<<<nwgI, 256, 0, stream>>>(emb, imps, W2af, W2bf, b2, out2, G);
}

// Round 17
// 198.933 us; speedup vs baseline: 1.9472x; 1.2510x over previous
//
#include <hip/hip_runtime.h>

typedef __attribute__((ext_vector_type(8))) short short8;
typedef __attribute__((ext_vector_type(4))) float f32x4;

static __device__ __forceinline__ unsigned short f2bf(float f) {
    union { float f; unsigned int u; } v; v.f = f;
    unsigned int r = v.u + 0x7fffu + ((v.u >> 16) & 1u);  // RNE
    return (unsigned short)(r >> 16);
}

static __device__ __forceinline__ float bf2f(unsigned short b) {
    union { unsigned int u; float f; } v; v.u = (unsigned int)b << 16; return v.f;
}

// HW packed f32->bf16 (RNE): one instruction per 2 elements (cuts the dominant
// VALU cost of the manual integer-RNE chain by ~8x).
static __device__ __forceinline__ short8 pack8(float4 a, float4 b) {
    union { unsigned int u[4]; short8 s; } r;
    asm("v_cvt_pk_bf16_f32 %0, %1, %2" : "=v"(r.u[0]) : "v"(a.x), "v"(a.y));
    asm("v_cvt_pk_bf16_f32 %0, %1, %2" : "=v"(r.u[1]) : "v"(a.z), "v"(a.w));
    asm("v_cvt_pk_bf16_f32 %0, %1, %2" : "=v"(r.u[2]) : "v"(b.x), "v"(b.y));
    asm("v_cvt_pk_bf16_f32 %0, %1, %2" : "=v"(r.u[3]) : "v"(b.z), "v"(b.w));
    return r.s;
}

static __device__ __forceinline__ void dma16(const void* g, void* l) {
    __builtin_amdgcn_global_load_lds(
        (const __attribute__((address_space(1))) unsigned int*)g,
        (__attribute__((address_space(3))) unsigned int*)l, 16, 0, 0);
}

static __device__ __forceinline__ float4 lds_rd16(const float* buf, int boff, int sw) {
    return *(const float4*)((const char*)buf + (boff ^ sw));
}

__global__ void k_zero(uint4* p, int n16) {
    int i = blockIdx.x * blockDim.x + threadIdx.x;
    if (i < n16) p[i] = uint4{0u, 0u, 0u, 0u};
}

// Pack W1,W2 (f32 [128][256]) into 4 fragment-ordered bf16 arrays:
// frag f=(wc*4+t)*4+kk, element [f*512 + lane*8 + j] -> contiguous 1KB bfr loads.
__global__ void k_convw(const float* __restrict__ W1, const float* __restrict__ W2,
                        unsigned short* W1af, unsigned short* W1bf,
                        unsigned short* W2af, unsigned short* W2bf) {
    int T = blockIdx.x * 256 + threadIdx.x;   // 8192 total
    int mat = T >> 11;
    int rem = T & 2047;
    int f = rem >> 6, lane = rem & 63;
    int wc = f >> 4, t = (f >> 2) & 3, kk = f & 3;
    int p = lane & 15, q = lane >> 4;
    int row = wc * 64 + t * 16 + p;
    int col = (mat & 1) * 128 + kk * 32 + q * 8;
    const float* src = (mat < 2 ? W1 : W2) + row * 256 + col;
    unsigned short* dst = (mat == 0 ? W1af : mat == 1 ? W1bf : mat == 2 ? W2af : W2bf);
    short8 v;
#pragma unroll
    for (int j = 0; j < 8; ++j) v[j] = (short)f2bf(src[j]);
    *(short8*)&dst[(size_t)f * 512 + lane * 8] = v;
}

__global__ void k_mark(const int* __restrict__ ids, int* __restrict__ cum, int n) {
    int i = blockIdx.x * blockDim.x + threadIdx.x;
    if (i < n) cum[ids[i]] = 1;
}

// 2-level scan: per-block inclusive scan of 1024 ints + block sums
__global__ __launch_bounds__(256) void k_scan1(int* __restrict__ cum, int* __restrict__ bsum, int G) {
    __shared__ int ws[4];
    int tid = threadIdx.x;
    int base = blockIdx.x * 1024 + tid * 4;
    int a0 = 0, a1 = 0, a2 = 0, a3 = 0;
    if (base + 0 < G) a0 = cum[base + 0];
    if (base + 1 < G) a1 = cum[base + 1];
    if (base + 2 < G) a2 = cum[base + 2];
    if (base + 3 < G) a3 = cum[base + 3];
    int s = a0 + a1 + a2 + a3;
    int lane = tid & 63;
    int v = s;
#pragma unroll
    for (int off = 1; off < 64; off <<= 1) {
        int u = __shfl_up(v, off, 64);
        if (lane >= off) v += u;
    }
    if (lane == 63) ws[tid >> 6] = v;
    __syncthreads();
    int wof = 0;
    for (int w = 0; w < (tid >> 6); ++w) wof += ws[w];
    int excl = wof + v - s;
    int r0 = excl + a0, r1 = r0 + a1, r2 = r1 + a2, r3 = r2 + a3;
    if (base + 0 < G) cum[base + 0] = r0;
    if (base + 1 < G) cum[base + 1] = r1;
    if (base + 2 < G) cum[base + 2] = r2;
    if (base + 3 < G) cum[base + 3] = r3;
    if (tid == 255) bsum[blockIdx.x] = excl + s;
}

__global__ void k_scan2(int* __restrict__ bsum, int nb) {
    int t = threadIdx.x;  // 64 threads, nb <= 64
    int v = (t < nb) ? bsum[t] : 0;
#pragma unroll
    for (int off = 1; off < 64; off <<= 1) {
        int u = __shfl_up(v, off, 64);
        if (t >= off) v += u;
    }
    if (t < nb) bsum[t] = v;
}

__global__ void k_gid(const int* __restrict__ ids, const int* __restrict__ cum,
                      const int* __restrict__ bsum, int* __restrict__ gid,
                      int* __restrict__ gstart, int* __restrict__ ngr, int n) {
    int i = blockIdx.x * blockDim.x + threadIdx.x;
    if (i >= n) return;
    int v = ids[i];
    int blk = v >> 10;
    int g = cum[v] + (blk ? bsum[blk - 1] : 0) - 1;
    gid[i] = g;
    if (i == 0 || ids[i - 1] != v) gstart[g] = i;
    if (i == n - 1) { gstart[g + 1] = n; *ngr = g + 1; }
}

// E1(bf16) = emb @ W1b^T + b1. 64-row block, LDS-staged, (256,4) occupancy.
__global__ __launch_bounds__(256, 4) void k_egemm(
    const float* __restrict__ emb, const unsigned short* __restrict__ Wf,
    const float* __restrict__ b1, unsigned short* __restrict__ E1b, int G) {
    __shared__ __align__(16) float ebuf[8192];   // 32KB: 64 rows f32
    int tid = threadIdx.x, lane = tid & 63, wid = tid >> 6;
    int p = lane & 15, q = lane >> 4;
    int wr = wid >> 1, wc = wid & 1;
    int row0 = blockIdx.x * 64;

    short8 bfr[4][4];
#pragma unroll
    for (int t = 0; t < 4; ++t)
#pragma unroll
        for (int kk = 0; kk < 4; ++kk)
            bfr[t][kk] = *(const short8*)&Wf[(size_t)((wc * 4 + t) * 4 + kk) * 512 + lane * 8];
    float b1v[4];
#pragma unroll
    for (int t = 0; t < 4; ++t) b1v[t] = b1[wc * 64 + t * 16 + p];

    long long maxb = (long long)G * 512 - 16;
#pragma unroll
    for (int k = 0; k < 8; ++k) {
        int doff = k * 4096 + tid * 16;
        int r = doff >> 9;
        long long s = (long long)(row0 + r) * 512 + (long long)((doff & 511) ^ ((r & 7) << 4));
        s = s < maxb ? s : maxb;
        dma16((const char*)emb + s, (char*)ebuf + doff);
    }
    asm volatile("s_waitcnt vmcnt(0)" ::: "memory");
    __builtin_amdgcn_s_barrier();
    __builtin_amdgcn_sched_barrier(0);

    int sw = (p & 7) << 4;
#pragma unroll
    for (int tt = 0; tt < 2; ++tt) {
        int lr = wr * 32 + tt * 16 + p;
        short8 afr[4];
#pragma unroll
        for (int kk = 0; kk < 4; ++kk) {
            int boff = lr * 512 + kk * 128 + q * 32;
            float4 v0 = lds_rd16(ebuf, boff, sw);
            float4 v1 = lds_rd16(ebuf, boff + 16, sw);
            afr[kk] = pack8(v0, v1);
        }
        f32x4 acc[4];
#pragma unroll
        for (int t = 0; t < 4; ++t) acc[t] = f32x4{0.f, 0.f, 0.f, 0.f};
#pragma unroll
        for (int t = 0; t < 4; ++t)
#pragma unroll
            for (int kk = 0; kk < 4; ++kk)
                acc[t] = __builtin_amdgcn_mfma_f32_16x16x32_bf16(afr[kk], bfr[t][kk], acc[t], 0, 0, 0);
#pragma unroll
        for (int t = 0; t < 4; ++t) {
            int colb = wc * 64 + t * 16 + p;
#pragma unroll
            for (int rg = 0; rg < 4; ++rg) {
                int rr = row0 + wr * 32 + tt * 16 + q * 4 + rg;
                if (rr < G) E1b[(size_t)rr * 128 + colb] = f2bf(acc[t][rg] + b1v[t]);
            }
        }
    }
}

// x_out = x @ W1a^T + E1[gid](bf16)  +  fused group means.
// Round-11 structure: 64-row block (32KB LDS), single vmcnt(0)+barrier,
// 4 blocks/CU. Scan windows = 32 rows; contained groups -> direct imps write;
// crossing -> atomicAdd into zeroed segsum (finished by k_fix).
// NOTE: nothing live across the barrier beyond gt/bfr — every attempt to hold
// more (hoisted gathers, two-phase DMA, 8-wave cap) spilled and regressed.
__global__ __launch_bounds__(256, 4) void k_xgemm(
    const float* __restrict__ x, const unsigned short* __restrict__ Wf,
    const int* __restrict__ gid, const unsigned short* __restrict__ E1b,
    const int* __restrict__ ngr,
    float* __restrict__ out, unsigned short* __restrict__ imps,
    float* __restrict__ segsum, int N, int nwg) {
    __shared__ __align__(16) float xbuf[8192];   // 32KB: 64 rows f32
    __shared__ int gids[64];
    int tid = threadIdx.x, lane = tid & 63, wid = tid >> 6;
    int p = lane & 15, q = lane >> 4;
    int wr = wid >> 1, wc = wid & 1;
    // bijective XCD swizzle (m204)
    int orig = blockIdx.x;
    int qq = nwg >> 3, rr8 = nwg & 7;
    int xcd = orig & 7, idx = orig >> 3;
    int bid = (xcd < rr8 ? xcd * (qq + 1) : rr8 * (qq + 1) + (xcd - rr8) * qq) + idx;
    int row0 = bid * 64;

    short8 bfr[4][4];
#pragma unroll
    for (int t = 0; t < 4; ++t)
#pragma unroll
        for (int kk = 0; kk < 4; ++kk)
            bfr[t][kk] = *(const short8*)&Wf[(size_t)((wc * 4 + t) * 4 + kk) * 512 + lane * 8];

    int gt[2];
#pragma unroll
    for (int tt = 0; tt < 2; ++tt)
        gt[tt] = gid[min(row0 + wr * 32 + tt * 16 + p, N - 1)];

    // scan geometry + edge loads (issued early, hidden under DMA)
    int c = tid & 127, h = tid >> 7;
    int lo = row0 + h * 32;
    int hi = min(lo + 32, N);
    int gbefore = -1, gafter = -1;
    if (lo > 0 && lo < N) gbefore = gid[lo - 1];
    if (hi < N) gafter = gid[hi];

    long long maxb = (long long)N * 512 - 16;
#pragma unroll
    for (int k = 0; k < 8; ++k) {
        int doff = k * 4096 + tid * 16;
        int r = doff >> 9;
        long long s = (long long)(row0 + r) * 512 + (long long)((doff & 511) ^ ((r & 7) << 4));
        s = s < maxb ? s : maxb;
        dma16((const char*)x + s, (char*)xbuf + doff);
    }
    if (wc == 0) {   // stage this block's gids into LDS (rows wr*32 .. wr*32+31)
#pragma unroll
        for (int tt = 0; tt < 2; ++tt)
            gids[wr * 32 + tt * 16 + p] = gt[tt];
    }
    asm volatile("s_waitcnt vmcnt(0) lgkmcnt(0)" ::: "memory");
    __builtin_amdgcn_s_barrier();
    __builtin_amdgcn_sched_barrier(0);

    int sw = (p & 7) << 4;
#pragma unroll
    for (int tt = 0; tt < 2; ++tt) {
        int lr = wr * 32 + tt * 16 + p;
        short8 afr[4];
#pragma unroll
        for (int kk = 0; kk < 4; ++kk) {
            int boff = lr * 512 + kk * 128 + q * 32;
            float4 v0 = lds_rd16(xbuf, boff, sw);
            float4 v1 = lds_rd16(xbuf, boff + 16, sw);
            afr[kk] = pack8(v0, v1);
        }
        int g4[4];
#pragma unroll
        for (int rg = 0; rg < 4; ++rg) g4[rg] = __shfl(gt[tt], q * 4 + rg);
        float ev[4][4];
#pragma unroll
        for (int t = 0; t < 4; ++t) {
            int colb = wc * 64 + t * 16 + p;
#pragma unroll
            for (int rg = 0; rg < 4; ++rg)
                ev[t][rg] = bf2f(E1b[(size_t)g4[rg] * 128 + colb]);
        }
        f32x4 acc[4];
#pragma unroll
        for (int t = 0; t < 4; ++t) acc[t] = f32x4{0.f, 0.f, 0.f, 0.f};
#pragma unroll
        for (int t = 0; t < 4; ++t)
#pragma unroll
            for (int kk = 0; kk < 4; ++kk)
                acc[t] = __builtin_amdgcn_mfma_f32_16x16x32_bf16(afr[kk], bfr[t][kk], acc[t], 0, 0, 0);
#pragma unroll
        for (int t = 0; t < 4; ++t) {
            int colb = wc * 64 + t * 16 + p;
#pragma unroll
            for (int rg = 0; rg < 4; ++rg) {
                int rr = row0 + wr * 32 + tt * 16 + q * 4 + rg;
                if (rr < N) out[(size_t)rr * 128 + colb] = acc[t][rg] + ev[t][rg];
            }
        }
    }

    // ---- fused group means from LDS (batched reads; 32-row window) ----
    if (lo < N) {
        int nwin = hi - lo;                 // 1..32
        int gbase = h * 32;
        int ng = *ngr;
        int gcur = gids[gbase];
        bool open_left = (gcur == gbefore);
        int rs = lo;
        float s = 0.f;
        for (int bb = 0; bb < nwin; bb += 8) {
            float v[8];
            int gn[8];
#pragma unroll
            for (int j = 0; j < 8; ++j) {
                int rr = bb + j; rr = rr < nwin - 1 ? rr : nwin - 1;
                int lrr = gbase + rr;
                v[j] = *(const float*)((const char*)xbuf + lrr * 512 + ((c * 4) ^ ((lrr & 7) << 4)));
                int rn = bb + j + 1; rn = rn < nwin - 1 ? rn : nwin - 1;
                gn[j] = gids[gbase + rn];
            }
#pragma unroll
            for (int j = 0; j < 8; ++j) {
                int r = bb + j;
                if (r < nwin) {
                    s += v[j];
                    bool at_end = (r + 1 >= nwin);
                    int gnext = at_end ? gafter : gn[j];
                    if (at_end || gnext != gcur) {
                        bool open_right = at_end && (gafter == gcur);
                        if (!open_left && !open_right) {
                            if (gcur < ng - 1)
                                imps[(size_t)gcur * 128 + c] = f2bf(s / (float)(lo + r + 1 - rs));
                        } else {
                            atomicAdd(&segsum[(size_t)gcur * 128 + c], s);
                        }
                        s = 0.f; rs = lo + r + 1; gcur = gnext; open_left = false;
                    }
                }
            }
        }
    }
}

// Finish crossing groups (segsum/n) and emb-copy for unwritten tail groups.
// Containment window = 32 rows (must mirror k_xgemm).
__global__ __launch_bounds__(256) void k_fix(
    const float* __restrict__ segsum, const float* __restrict__ emb,
    const int* __restrict__ gstart, const int* __restrict__ ngr,
    unsigned short* __restrict__ imps, int G) {
    int g = blockIdx.x * 4 + (threadIdx.x >> 6);
    int lane = threadIdx.x & 63;
    if (g >= G) return;
    int ng = *ngr;
    float2 m;
    if (g < ng - 1) {
        int a = gstart[g], b = gstart[g + 1];
        if ((a >> 5) == ((b - 1) >> 5)) return;  // contained: imps already written
        float inv = 1.0f / (float)(b - a);
        float2 s = *(const float2*)&segsum[(size_t)g * 128 + lane * 2];
        m.x = s.x * inv; m.y = s.y * inv;
    } else {
        m = *(const float2*)&emb[(size_t)g * 128 + lane * 2];
    }
    unsigned int pk = (unsigned int)f2bf(m.x) | ((unsigned int)f2bf(m.y) << 16);
    ((unsigned int*)imps)[(size_t)g * 64 + lane] = pk;
}

// imputed_out = emb @ W2a^T + imps @ W2b^T + b2. 64-row block, LDS-staged.
__global__ __launch_bounds__(256, 2) void k_igemm(
    const float* __restrict__ emb, const unsigned short* __restrict__ imps,
    const unsigned short* __restrict__ Waf, const unsigned short* __restrict__ Wbf,
    const float* __restrict__ b2, float* __restrict__ out2, int G) {
    __shared__ __align__(16) float ebuf[8192];            // 32KB: 64 rows f32
    __shared__ __align__(16) unsigned short ibuf[8192];   // 16KB: 64 rows bf16
    int tid = threadIdx.x, lane = tid & 63, wid = tid >> 6;
    int p = lane & 15, q = lane >> 4;
    int wr = wid >> 1, wc = wid & 1;
    int row0 = blockIdx.x * 64;

    short8 bfrA[4][4], bfrB[4][4];
#pragma unroll
    for (int t = 0; t < 4; ++t)
#pragma unroll
        for (int kk = 0; kk < 4; ++kk) {
            bfrA[t][kk] = *(const short8*)&Waf[(size_t)((wc * 4 + t) * 4 + kk) * 512 + lane * 8];
            bfrB[t][kk] = *(const short8*)&Wbf[(size_t)((wc * 4 + t) * 4 + kk) * 512 + lane * 8];
        }
    float b2v[4];
#pragma unroll
    for (int t = 0; t < 4; ++t) b2v[t] = b2[wc * 64 + t * 16 + p];

    long long maxe = (long long)G * 512 - 16;
    long long maxi = (long long)G * 256 - 16;
#pragma unroll
    for (int k = 0; k < 8; ++k) {
        int doff = k * 4096 + tid * 16;
        int r = doff >> 9;
        long long s = (long long)(row0 + r) * 512 + (long long)((doff & 511) ^ ((r & 7) << 4));
        s = s < maxe ? s : maxe;
        dma16((const char*)emb + s, (char*)ebuf + doff);
    }
#pragma unroll
    for (int k = 0; k < 4; ++k) {
        int doff = k * 4096 + tid * 16;
        int r = doff >> 8;
        long long s = (long long)(row0 + r) * 256 + (long long)((doff & 255) ^ ((r & 7) << 4));
        s = s < maxi ? s : maxi;
        dma16((const char*)imps + s, (char*)ibuf + doff);
    }
    asm volatile("s_waitcnt vmcnt(0)" ::: "memory");
    __builtin_amdgcn_s_barrier();
    __builtin_amdgcn_sched_barrier(0);

    int sw = (p & 7) << 4;
#pragma unroll
    for (int tt = 0; tt < 2; ++tt) {
        int lr = wr * 32 + tt * 16 + p;
        short8 ae[4], ia[4];
#pragma unroll
        for (int kk = 0; kk < 4; ++kk) {
            int boff = lr * 512 + kk * 128 + q * 32;
            float4 v0 = lds_rd16(ebuf, boff, sw);
            float4 v1 = lds_rd16(ebuf, boff + 16, sw);
            ae[kk] = pack8(v0, v1);
            int boff2 = lr * 256 + ((kk * 64 + q * 16) ^ sw);
            ia[kk] = *(const short8*)((const char*)ibuf + boff2);
        }
        f32x4 acc[4];
#pragma unroll
        for (int t = 0; t < 4; ++t) acc[t] = f32x4{0.f, 0.f, 0.f, 0.f};
#pragma unroll
        for (int kk = 0; kk < 4; ++kk)
#pragma unroll
            for (int t = 0; t < 4; ++t) {
                acc[t] = __builtin_amdgcn_mfma_f32_16x16x32_bf16(ae[kk], bfrA[t][kk], acc[t], 0, 0, 0);
                acc[t] = __builtin_amdgcn_mfma_f32_16x16x32_bf16(ia[kk], bfrB[t][kk], acc[t], 0, 0, 0);
            }
#pragma unroll
        for (int t = 0; t < 4; ++t) {
            int colb = wc * 64 + t * 16 + p;
#pragma unroll
            for (int rg = 0; rg < 4; ++rg) {
                int rr = row0 + wr * 32 + tt * 16 + q * 4 + rg;
                if (rr < G) out2[(size_t)rr * 128 + colb] = acc[t][rg] + b2v[t];
            }
        }
    }
}

extern "C" void kernel_launch(void* const* d_in, const int* in_sizes, int n_in,
                              void* d_out, int out_size, void* d_ws, size_t ws_size,
                              hipStream_t stream) {
    const float* x   = (const float*)d_in[0];
    const float* emb = (const float*)d_in[1];
    const float* W1  = (const float*)d_in[2];
    const float* b1  = (const float*)d_in[3];
    const float* W2  = (const float*)d_in[4];
    const float* b2  = (const float*)d_in[5];
    const int*   ids = (const int*)d_in[6];
    const int H = 128;
    const int N = in_sizes[6];
    const int G = in_sizes[1] / H;

    float* out  = (float*)d_out;
    float* out2 = out + (size_t)N * H;

    char* ws = (char*)d_ws;
    size_t off = 0;
    float* segsum = (float*)(ws + off); off += (size_t)G * H * 4;
    int*   cum    = (int*)(ws + off);   off += (size_t)G * 4;
    size_t zbytes = off;                              // zero region: segsum + cum
    off = (off + 255) & ~(size_t)255;
    int* bsum   = (int*)(ws + off); off += 64 * 4;          off = (off + 255) & ~(size_t)255;
    int* gid    = (int*)(ws + off); off += (size_t)N * 4;   off = (off + 255) & ~(size_t)255;
    int* gstart = (int*)(ws + off); off += (size_t)(G + 1) * 4; off = (off + 255) & ~(size_t)255;
    int* ngr    = (int*)(ws + off); off += 256;
    unsigned short* W1af = (unsigned short*)(ws + off); off += (size_t)H * H * 2;
    unsigned short* W1bf = (unsigned short*)(ws + off); off += (size_t)H * H * 2;
    unsigned short* W2af = (unsigned short*)(ws + off); off += (size_t)H * H * 2;
    unsigned short* W2bf = (unsigned short*)(ws + off); off += (size_t)H * H * 2;
    unsigned short* imps = (unsigned short*)(ws + off); off += (size_t)G * H * 2;
    unsigned short* E1b  = (unsigned short*)(ws + off); off += (size_t)G * H * 2;

    int n16 = (int)((zbytes + 15) / 16);
    int nb = (G + 1023) >> 10;
    int nwgX = (N + 63) >> 6;
    int nwgE = (G + 63) >> 6;
    int nwgI = (G + 63) >> 6;
    k_zero<<<(n16 + 255) / 256, 256, 0, stream>>>((uint4*)ws, n16);
    k_convw<<<32, 256, 0, stream>>>(W1, W2, W1af, W1bf, W2af, W2bf);
    k_mark<<<(N + 255) / 256, 256, 0, stream>>>(ids, cum, N);
    k_scan1<<<nb, 256, 0, stream>>>(cum, bsum, G);
    k_scan2<<<1, 64, 0, stream>>>(bsum, nb);
    k_gid<<<(N + 255) / 256, 256, 0, stream>>>(ids, cum, bsum, gid, gstart, ngr, N);
    k_egemm<<<nwgE, 256, 0, stream>>>(emb, W1bf, b1, E1b, G);
    k_xgemm<<<nwgX, 256, 0, stream>>>(x, W1af, gid, E1b, ngr, out, imps, segsum, N, nwgX);
    k_fix<<<(G + 3) / 4, 256, 0, stream>>>(segsum, emb, gstart, ngr, imps, G);
    k_igemm<<<nwgI, 256, 0, stream>>>(emb, imps, W2af, W2bf, b2, out2, G);
}

// Round 18
// 182.439 us; speedup vs baseline: 2.1233x; 1.0904x over previous
//
#include <hip/hip_runtime.h>

typedef __attribute__((ext_vector_type(8))) short short8;
typedef __attribute__((ext_vector_type(4))) float f32x4;

static __device__ __forceinline__ unsigned short f2bf(float f) {
    union { float f; unsigned int u; } v; v.f = f;
    unsigned int r = v.u + 0x7fffu + ((v.u >> 16) & 1u);  // RNE
    return (unsigned short)(r >> 16);
}

static __device__ __forceinline__ float bf2f(unsigned short b) {
    union { unsigned int u; float f; } v; v.u = (unsigned int)b << 16; return v.f;
}

// HW packed f32->bf16 (RNE): one instruction per 2 elements.
static __device__ __forceinline__ short8 pack8(float4 a, float4 b) {
    union { unsigned int u[4]; short8 s; } r;
    asm("v_cvt_pk_bf16_f32 %0, %1, %2" : "=v"(r.u[0]) : "v"(a.x), "v"(a.y));
    asm("v_cvt_pk_bf16_f32 %0, %1, %2" : "=v"(r.u[1]) : "v"(a.z), "v"(a.w));
    asm("v_cvt_pk_bf16_f32 %0, %1, %2" : "=v"(r.u[2]) : "v"(b.x), "v"(b.y));
    asm("v_cvt_pk_bf16_f32 %0, %1, %2" : "=v"(r.u[3]) : "v"(b.z), "v"(b.w));
    return r.s;
}

static __device__ __forceinline__ void dma16(const void* g, void* l) {
    __builtin_amdgcn_global_load_lds(
        (const __attribute__((address_space(1))) unsigned int*)g,
        (__attribute__((address_space(3))) unsigned int*)l, 16, 0, 0);
}

static __device__ __forceinline__ float4 lds_rd16(const float* buf, int boff, int sw) {
    return *(const float4*)((const char*)buf + (boff ^ sw));
}

__global__ void k_zero(uint4* p, int n16) {
    int i = blockIdx.x * blockDim.x + threadIdx.x;
    if (i < n16) p[i] = uint4{0u, 0u, 0u, 0u};
}

// Pack W1,W2 (f32 [128][256]) into 4 fragment-ordered bf16 arrays.
__global__ void k_convw(const float* __restrict__ W1, const float* __restrict__ W2,
                        unsigned short* W1af, unsigned short* W1bf,
                        unsigned short* W2af, unsigned short* W2bf) {
    int T = blockIdx.x * 256 + threadIdx.x;   // 8192 total
    int mat = T >> 11;
    int rem = T & 2047;
    int f = rem >> 6, lane = rem & 63;
    int wc = f >> 4, t = (f >> 2) & 3, kk = f & 3;
    int p = lane & 15, q = lane >> 4;
    int row = wc * 64 + t * 16 + p;
    int col = (mat & 1) * 128 + kk * 32 + q * 8;
    const float* src = (mat < 2 ? W1 : W2) + row * 256 + col;
    unsigned short* dst = (mat == 0 ? W1af : mat == 1 ? W1bf : mat == 2 ? W2af : W2bf);
    short8 v;
#pragma unroll
    for (int j = 0; j < 8; ++j) v[j] = (short)f2bf(src[j]);
    *(short8*)&dst[(size_t)f * 512 + lane * 8] = v;
}

__global__ void k_mark(const int* __restrict__ ids, int* __restrict__ cum, int n) {
    int i = blockIdx.x * blockDim.x + threadIdx.x;
    if (i < n) cum[ids[i]] = 1;
}

// 2-level scan: per-block inclusive scan of 1024 ints + block sums
__global__ __launch_bounds__(256) void k_scan1(int* __restrict__ cum, int* __restrict__ bsum, int G) {
    __shared__ int ws[4];
    int tid = threadIdx.x;
    int base = blockIdx.x * 1024 + tid * 4;
    int a0 = 0, a1 = 0, a2 = 0, a3 = 0;
    if (base + 0 < G) a0 = cum[base + 0];
    if (base + 1 < G) a1 = cum[base + 1];
    if (base + 2 < G) a2 = cum[base + 2];
    if (base + 3 < G) a3 = cum[base + 3];
    int s = a0 + a1 + a2 + a3;
    int lane = tid & 63;
    int v = s;
#pragma unroll
    for (int off = 1; off < 64; off <<= 1) {
        int u = __shfl_up(v, off, 64);
        if (lane >= off) v += u;
    }
    if (lane == 63) ws[tid >> 6] = v;
    __syncthreads();
    int wof = 0;
    for (int w = 0; w < (tid >> 6); ++w) wof += ws[w];
    int excl = wof + v - s;
    int r0 = excl + a0, r1 = r0 + a1, r2 = r1 + a2, r3 = r2 + a3;
    if (base + 0 < G) cum[base + 0] = r0;
    if (base + 1 < G) cum[base + 1] = r1;
    if (base + 2 < G) cum[base + 2] = r2;
    if (base + 3 < G) cum[base + 3] = r3;
    if (tid == 255) bsum[blockIdx.x] = excl + s;
}

__global__ void k_scan2(int* __restrict__ bsum, int nb) {
    int t = threadIdx.x;  // 64 threads, nb <= 64
    int v = (t < nb) ? bsum[t] : 0;
#pragma unroll
    for (int off = 1; off < 64; off <<= 1) {
        int u = __shfl_up(v, off, 64);
        if (t >= off) v += u;
    }
    if (t < nb) bsum[t] = v;
}

__global__ void k_gid(const int* __restrict__ ids, const int* __restrict__ cum,
                      const int* __restrict__ bsum, int* __restrict__ gid,
                      int* __restrict__ gstart, int* __restrict__ ngr, int n) {
    int i = blockIdx.x * blockDim.x + threadIdx.x;
    if (i >= n) return;
    int v = ids[i];
    int blk = v >> 10;
    int g = cum[v] + (blk ? bsum[blk - 1] : 0) - 1;
    gid[i] = g;
    if (i == 0 || ids[i - 1] != v) gstart[g] = i;
    if (i == n - 1) { gstart[g + 1] = n; *ngr = g + 1; }
}

// E1(bf16) = emb @ W1b^T + b1. 64-row block, LDS-staged, (256,4) occupancy.
__global__ __launch_bounds__(256, 4) void k_egemm(
    const float* __restrict__ emb, const unsigned short* __restrict__ Wf,
    const float* __restrict__ b1, unsigned short* __restrict__ E1b, int G) {
    __shared__ __align__(16) float ebuf[8192];   // 32KB: 64 rows f32
    int tid = threadIdx.x, lane = tid & 63, wid = tid >> 6;
    int p = lane & 15, q = lane >> 4;
    int wr = wid >> 1, wc = wid & 1;
    int row0 = blockIdx.x * 64;

    short8 bfr[4][4];
#pragma unroll
    for (int t = 0; t < 4; ++t)
#pragma unroll
        for (int kk = 0; kk < 4; ++kk)
            bfr[t][kk] = *(const short8*)&Wf[(size_t)((wc * 4 + t) * 4 + kk) * 512 + lane * 8];
    float b1v[4];
#pragma unroll
    for (int t = 0; t < 4; ++t) b1v[t] = b1[wc * 64 + t * 16 + p];

    long long maxb = (long long)G * 512 - 16;
#pragma unroll
    for (int k = 0; k < 8; ++k) {
        int doff = k * 4096 + tid * 16;
        int r = doff >> 9;
        long long s = (long long)(row0 + r) * 512 + (long long)((doff & 511) ^ ((r & 7) << 4));
        s = s < maxb ? s : maxb;
        dma16((const char*)emb + s, (char*)ebuf + doff);
    }
    asm volatile("s_waitcnt vmcnt(0)" ::: "memory");
    __builtin_amdgcn_s_barrier();
    __builtin_amdgcn_sched_barrier(0);

    int sw = (p & 7) << 4;
#pragma unroll
    for (int tt = 0; tt < 2; ++tt) {
        int lr = wr * 32 + tt * 16 + p;
        short8 afr[4];
#pragma unroll
        for (int kk = 0; kk < 4; ++kk) {
            int boff = lr * 512 + kk * 128 + q * 32;
            float4 v0 = lds_rd16(ebuf, boff, sw);
            float4 v1 = lds_rd16(ebuf, boff + 16, sw);
            afr[kk] = pack8(v0, v1);
        }
        f32x4 acc[4];
#pragma unroll
        for (int t = 0; t < 4; ++t) acc[t] = f32x4{0.f, 0.f, 0.f, 0.f};
#pragma unroll
        for (int t = 0; t < 4; ++t)
#pragma unroll
            for (int kk = 0; kk < 4; ++kk)
                acc[t] = __builtin_amdgcn_mfma_f32_16x16x32_bf16(afr[kk], bfr[t][kk], acc[t], 0, 0, 0);
#pragma unroll
        for (int t = 0; t < 4; ++t) {
            int colb = wc * 64 + t * 16 + p;
#pragma unroll
            for (int rg = 0; rg < 4; ++rg) {
                int rr = row0 + wr * 32 + tt * 16 + q * 4 + rg;
                if (rr < G) E1b[(size_t)rr * 128 + colb] = f2bf(acc[t][rg] + b1v[t]);
            }
        }
    }
}

// x_out = x @ W1a^T + E1[gid](bf16)  +  fused group means.
// Round-14 structure + E1 gather moved into the DMA queue: per-lane global
// source (gid-dependent, pre-swizzled) -> linear LDS e1buf. Zero register
// cost; gathers drain with the x DMAs. Post-barrier ev = cheap LDS read.
__global__ __launch_bounds__(256, 4) void k_xgemm(
    const float* __restrict__ x, const unsigned short* __restrict__ Wf,
    const int* __restrict__ gid, const unsigned short* __restrict__ E1b,
    const int* __restrict__ ngr,
    float* __restrict__ out, unsigned short* __restrict__ imps,
    float* __restrict__ segsum, int N, int nwg) {
    __shared__ __align__(16) float xbuf[8192];             // 32KB: 64 rows f32
    __shared__ __align__(16) unsigned short e1buf[8192];   // 16KB: 64 rows bf16
    __shared__ int gids[64];
    int tid = threadIdx.x, lane = tid & 63, wid = tid >> 6;
    int p = lane & 15, q = lane >> 4;
    int wr = wid >> 1, wc = wid & 1;
    // bijective XCD swizzle (m204)
    int orig = blockIdx.x;
    int qq = nwg >> 3, rr8 = nwg & 7;
    int xcd = orig & 7, idx = orig >> 3;
    int bid = (xcd < rr8 ? xcd * (qq + 1) : rr8 * (qq + 1) + (xcd - rr8) * qq) + idx;
    int row0 = bid * 64;

    short8 bfr[4][4];
#pragma unroll
    for (int t = 0; t < 4; ++t)
#pragma unroll
        for (int kk = 0; kk < 4; ++kk)
            bfr[t][kk] = *(const short8*)&Wf[(size_t)((wc * 4 + t) * 4 + kk) * 512 + lane * 8];

    int gt[2];
#pragma unroll
    for (int tt = 0; tt < 2; ++tt)
        gt[tt] = gid[min(row0 + wr * 32 + tt * 16 + p, N - 1)];
    // gids for the E1-DMA addressing: thread covers rows k*16 + (tid>>4)
    int gd[4];
#pragma unroll
    for (int k = 0; k < 4; ++k)
        gd[k] = gid[min(row0 + k * 16 + (tid >> 4), N - 1)];

    // scan geometry + edge loads (issued early, hidden under DMA)
    int c = tid & 127, h = tid >> 7;
    int lo = row0 + h * 32;
    int hi = min(lo + 32, N);
    int gbefore = -1, gafter = -1;
    if (lo > 0 && lo < N) gbefore = gid[lo - 1];
    if (hi < N) gafter = gid[hi];

    long long maxb = (long long)N * 512 - 16;
#pragma unroll
    for (int k = 0; k < 8; ++k) {
        int doff = k * 4096 + tid * 16;
        int r = doff >> 9;
        long long s = (long long)(row0 + r) * 512 + (long long)((doff & 511) ^ ((r & 7) << 4));
        s = s < maxb ? s : maxb;
        dma16((const char*)x + s, (char*)xbuf + doff);
    }
    // E1 gather via DMA: row r = k*16 + tid>>4, 16B per lane, swizzled source
#pragma unroll
    for (int k = 0; k < 4; ++k) {
        int doff = k * 4096 + tid * 16;                 // dest byte in e1buf
        int r = doff >> 8;                              // local row (256B/row)
        long long s = (long long)gd[k] * 256 + (long long)((doff & 255) ^ ((r & 7) << 4));
        dma16((const char*)E1b + s, (char*)e1buf + doff);
    }
    if (wc == 0) {   // stage this block's gids into LDS (rows wr*32 .. wr*32+31)
#pragma unroll
        for (int tt = 0; tt < 2; ++tt)
            gids[wr * 32 + tt * 16 + p] = gt[tt];
    }
    asm volatile("s_waitcnt vmcnt(0) lgkmcnt(0)" ::: "memory");
    __builtin_amdgcn_s_barrier();
    __builtin_amdgcn_sched_barrier(0);

    int sw = (p & 7) << 4;
#pragma unroll
    for (int tt = 0; tt < 2; ++tt) {
        int lr = wr * 32 + tt * 16 + p;
        short8 afr[4];
#pragma unroll
        for (int kk = 0; kk < 4; ++kk) {
            int boff = lr * 512 + kk * 128 + q * 32;
            float4 v0 = lds_rd16(xbuf, boff, sw);
            float4 v1 = lds_rd16(xbuf, boff + 16, sw);
            afr[kk] = pack8(v0, v1);
        }
        float ev[4][4];
#pragma unroll
        for (int t = 0; t < 4; ++t) {
            int colb = wc * 64 + t * 16 + p;
#pragma unroll
            for (int rg = 0; rg < 4; ++rg) {
                int lr2 = wr * 32 + tt * 16 + q * 4 + rg;
                int byte = lr2 * 256 + ((colb * 2) ^ ((lr2 & 7) << 4));
                ev[t][rg] = bf2f(*(const unsigned short*)((const char*)e1buf + byte));
            }
        }
        f32x4 acc[4];
#pragma unroll
        for (int t = 0; t < 4; ++t) acc[t] = f32x4{0.f, 0.f, 0.f, 0.f};
#pragma unroll
        for (int t = 0; t < 4; ++t)
#pragma unroll
            for (int kk = 0; kk < 4; ++kk)
                acc[t] = __builtin_amdgcn_mfma_f32_16x16x32_bf16(afr[kk], bfr[t][kk], acc[t], 0, 0, 0);
#pragma unroll
        for (int t = 0; t < 4; ++t) {
            int colb = wc * 64 + t * 16 + p;
#pragma unroll
            for (int rg = 0; rg < 4; ++rg) {
                int rr = row0 + wr * 32 + tt * 16 + q * 4 + rg;
                if (rr < N) out[(size_t)rr * 128 + colb] = acc[t][rg] + ev[t][rg];
            }
        }
    }

    // ---- fused group means from LDS (batched reads; 32-row window) ----
    if (lo < N) {
        int nwin = hi - lo;                 // 1..32
        int gbase = h * 32;
        int ng = *ngr;
        int gcur = gids[gbase];
        bool open_left = (gcur == gbefore);
        int rs = lo;
        float s = 0.f;
        for (int bb = 0; bb < nwin; bb += 8) {
            float v[8];
            int gn[8];
#pragma unroll
            for (int j = 0; j < 8; ++j) {
                int rr = bb + j; rr = rr < nwin - 1 ? rr : nwin - 1;
                int lrr = gbase + rr;
                v[j] = *(const float*)((const char*)xbuf + lrr * 512 + ((c * 4) ^ ((lrr & 7) << 4)));
                int rn = bb + j + 1; rn = rn < nwin - 1 ? rn : nwin - 1;
                gn[j] = gids[gbase + rn];
            }
#pragma unroll
            for (int j = 0; j < 8; ++j) {
                int r = bb + j;
                if (r < nwin) {
                    s += v[j];
                    bool at_end = (r + 1 >= nwin);
                    int gnext = at_end ? gafter : gn[j];
                    if (at_end || gnext != gcur) {
                        bool open_right = at_end && (gafter == gcur);
                        if (!open_left && !open_right) {
                            if (gcur < ng - 1)
                                imps[(size_t)gcur * 128 + c] = f2bf(s / (float)(lo + r + 1 - rs));
                        } else {
                            atomicAdd(&segsum[(size_t)gcur * 128 + c], s);
                        }
                        s = 0.f; rs = lo + r + 1; gcur = gnext; open_left = false;
                    }
                }
            }
        }
    }
}

// Finish crossing groups (segsum/n) and emb-copy for unwritten tail groups.
// Containment window = 32 rows (must mirror k_xgemm).
__global__ __launch_bounds__(256) void k_fix(
    const float* __restrict__ segsum, const float* __restrict__ emb,
    const int* __restrict__ gstart, const int* __restrict__ ngr,
    unsigned short* __restrict__ imps, int G) {
    int g = blockIdx.x * 4 + (threadIdx.x >> 6);
    int lane = threadIdx.x & 63;
    if (g >= G) return;
    int ng = *ngr;
    float2 m;
    if (g < ng - 1) {
        int a = gstart[g], b = gstart[g + 1];
        if ((a >> 5) == ((b - 1) >> 5)) return;  // contained: imps already written
        float inv = 1.0f / (float)(b - a);
        float2 s = *(const float2*)&segsum[(size_t)g * 128 + lane * 2];
        m.x = s.x * inv; m.y = s.y * inv;
    } else {
        m = *(const float2*)&emb[(size_t)g * 128 + lane * 2];
    }
    unsigned int pk = (unsigned int)f2bf(m.x) | ((unsigned int)f2bf(m.y) << 16);
    ((unsigned int*)imps)[(size_t)g * 64 + lane] = pk;
}

// imputed_out = emb @ W2a^T + imps @ W2b^T + b2. 64-row block, LDS-staged.
__global__ __launch_bounds__(256, 2) void k_igemm(
    const float* __restrict__ emb, const unsigned short* __restrict__ imps,
    const unsigned short* __restrict__ Waf, const unsigned short* __restrict__ Wbf,
    const float* __restrict__ b2, float* __restrict__ out2, int G) {
    __shared__ __align__(16) float ebuf[8192];            // 32KB: 64 rows f32
    __shared__ __align__(16) unsigned short ibuf[8192];   // 16KB: 64 rows bf16
    int tid = threadIdx.x, lane = tid & 63, wid = tid >> 6;
    int p = lane & 15, q = lane >> 4;
    int wr = wid >> 1, wc = wid & 1;
    int row0 = blockIdx.x * 64;

    short8 bfrA[4][4], bfrB[4][4];
#pragma unroll
    for (int t = 0; t < 4; ++t)
#pragma unroll
        for (int kk = 0; kk < 4; ++kk) {
            bfrA[t][kk] = *(const short8*)&Waf[(size_t)((wc * 4 + t) * 4 + kk) * 512 + lane * 8];
            bfrB[t][kk] = *(const short8*)&Wbf[(size_t)((wc * 4 + t) * 4 + kk) * 512 + lane * 8];
        }
    float b2v[4];
#pragma unroll
    for (int t = 0; t < 4; ++t) b2v[t] = b2[wc * 64 + t * 16 + p];

    long long maxe = (long long)G * 512 - 16;
    long long maxi = (long long)G * 256 - 16;
#pragma unroll
    for (int k = 0; k < 8; ++k) {
        int doff = k * 4096 + tid * 16;
        int r = doff >> 9;
        long long s = (long long)(row0 + r) * 512 + (long long)((doff & 511) ^ ((r & 7) << 4));
        s = s < maxe ? s : maxe;
        dma16((const char*)emb + s, (char*)ebuf + doff);
    }
#pragma unroll
    for (int k = 0; k < 4; ++k) {
        int doff = k * 4096 + tid * 16;
        int r = doff >> 8;
        long long s = (long long)(row0 + r) * 256 + (long long)((doff & 255) ^ ((r & 7) << 4));
        s = s < maxi ? s : maxi;
        dma16((const char*)imps + s, (char*)ibuf + doff);
    }
    asm volatile("s_waitcnt vmcnt(0)" ::: "memory");
    __builtin_amdgcn_s_barrier();
    __builtin_amdgcn_sched_barrier(0);

    int sw = (p & 7) << 4;
#pragma unroll
    for (int tt = 0; tt < 2; ++tt) {
        int lr = wr * 32 + tt * 16 + p;
        short8 ae[4], ia[4];
#pragma unroll
        for (int kk = 0; kk < 4; ++kk) {
            int boff = lr * 512 + kk * 128 + q * 32;
            float4 v0 = lds_rd16(ebuf, boff, sw);
            float4 v1 = lds_rd16(ebuf, boff + 16, sw);
            ae[kk] = pack8(v0, v1);
            int boff2 = lr * 256 + ((kk * 64 + q * 16) ^ sw);
            ia[kk] = *(const short8*)((const char*)ibuf + boff2);
        }
        f32x4 acc[4];
#pragma unroll
        for (int t = 0; t < 4; ++t) acc[t] = f32x4{0.f, 0.f, 0.f, 0.f};
#pragma unroll
        for (int kk = 0; kk < 4; ++kk)
#pragma unroll
            for (int t = 0; t < 4; ++t) {
                acc[t] = __builtin_amdgcn_mfma_f32_16x16x32_bf16(ae[kk], bfrA[t][kk], acc[t], 0, 0, 0);
                acc[t] = __builtin_amdgcn_mfma_f32_16x16x32_bf16(ia[kk], bfrB[t][kk], acc[t], 0, 0, 0);
            }
#pragma unroll
        for (int t = 0; t < 4; ++t) {
            int colb = wc * 64 + t * 16 + p;
#pragma unroll
            for (int rg = 0; rg < 4; ++rg) {
                int rr = row0 + wr * 32 + tt * 16 + q * 4 + rg;
                if (rr < G) out2[(size_t)rr * 128 + colb] = acc[t][rg] + b2v[t];
            }
        }
    }
}

extern "C" void kernel_launch(void* const* d_in, const int* in_sizes, int n_in,
                              void* d_out, int out_size, void* d_ws, size_t ws_size,
                              hipStream_t stream) {
    const float* x   = (const float*)d_in[0];
    const float* emb = (const float*)d_in[1];
    const float* W1  = (const float*)d_in[2];
    const float* b1  = (const float*)d_in[3];
    const float* W2  = (const float*)d_in[4];
    const float* b2  = (const float*)d_in[5];
    const int*   ids = (const int*)d_in[6];
    const int H = 128;
    const int N = in_sizes[6];
    const int G = in_sizes[1] / H;

    float* out  = (float*)d_out;
    float* out2 = out + (size_t)N * H;

    char* ws = (char*)d_ws;
    size_t off = 0;
    float* segsum = (float*)(ws + off); off += (size_t)G * H * 4;
    int*   cum    = (int*)(ws + off);   off += (size_t)G * 4;
    size_t zbytes = off;                              // zero region: segsum + cum
    off = (off + 255) & ~(size_t)255;
    int* bsum   = (int*)(ws + off); off += 64 * 4;          off = (off + 255) & ~(size_t)255;
    int* gid    = (int*)(ws + off); off += (size_t)N * 4;   off = (off + 255) & ~(size_t)255;
    int* gstart = (int*)(ws + off); off += (size_t)(G + 1) * 4; off = (off + 255) & ~(size_t)255;
    int* ngr    = (int*)(ws + off); off += 256;
    unsigned short* W1af = (unsigned short*)(ws + off); off += (size_t)H * H * 2;
    unsigned short* W1bf = (unsigned short*)(ws + off); off += (size_t)H * H * 2;
    unsigned short* W2af = (unsigned short*)(ws + off); off += (size_t)H * H * 2;
    unsigned short* W2bf = (unsigned short*)(ws + off); off += (size_t)H * H * 2;
    unsigned short* imps = (unsigned short*)(ws + off); off += (size_t)G * H * 2;
    unsigned short* E1b  = (unsigned short*)(ws + off); off += (size_t)G * H * 2;

    int n16 = (int)((zbytes + 15) / 16);
    int nb = (G + 1023) >> 10;
    int nwgX = (N + 63) >> 6;
    int nwgE = (G + 63) >> 6;
    int nwgI = (G + 63) >> 6;
    k_zero<<<(n16 + 255) / 256, 256, 0, stream>>>((uint4*)ws, n16);
    k_convw<<<32, 256, 0, stream>>>(W1, W2, W1af, W1bf, W2af, W2bf);
    k_mark<<<(N + 255) / 256, 256, 0, stream>>>(ids, cum, N);
    k_scan1<<<nb, 256, 0, stream>>>(cum, bsum, G);
    k_scan2<<<1, 64, 0, stream>>>(bsum, nb);
    k_gid<<<(N + 255) / 256, 256, 0, stream>>>(ids, cum, bsum, gid, gstart, ngr, N);
    k_egemm<<<nwgE, 256, 0, stream>>>(emb, W1bf, b1, E1b, G);
    k_xgemm<<<nwgX, 256, 0, stream>>>(x, W1af, gid, E1b, ngr, out, imps, segsum, N, nwgX);
    k_fix<<<(G + 3) / 4, 256, 0, stream>>>(segsum, emb, gstart, ngr, imps, G);
    k_igemm<<<nwgI, 256, 0, stream>>>(emb, imps, W2af, W2bf, b2, out2, G);
}